// Round 1
// baseline (2046.060 us; speedup 1.0000x reference)
//
#include <hip/hip_runtime.h>
#include <cstdio>
#include <cstdint>

// ---------------------------------------------------------------------------
// Fused transformer block (B=4,S=1024,D=1024,H=16,KVH=4,E=8,TOPK=2,FF=2816)
// Strategy R1: fp32-exact pre-gate path (flip-proof top-2 gating),
//             bf16 MFMA grouped MoE (post-gate, tolerance probe).
// ---------------------------------------------------------------------------

typedef __attribute__((ext_vector_type(4))) int   int4v;
typedef __attribute__((ext_vector_type(8))) short short8;
typedef __attribute__((ext_vector_type(4))) float f32x4;

constexpr int Tn  = 4096;   // B*S tokens
constexpr int Dm  = 1024;   // model dim
constexpr int Hh  = 16;     // heads
constexpr int Ss  = 1024;   // seq
constexpr int Ee  = 8;      // experts
constexpr int FFf = 2816;   // expert hidden

__device__ __forceinline__ unsigned short f2bf(float f) {
  union { float f; unsigned u; } v; v.f = f;
  unsigned r = v.u + 0x7FFFu + ((v.u >> 16) & 1u);
  return (unsigned short)(r >> 16);
}

// ---------------------------------------------------------------------------
// RMSNorm #1: xf = ln1_w * hidden * rsqrt(mean(hidden^2)+eps)
__global__ __launch_bounds__(256) void rms1_kernel(const float* __restrict__ x,
                                                   const float* __restrict__ w,
                                                   float* __restrict__ out) {
  const int t = blockIdx.x, tid = threadIdx.x;
  float4 v = *(const float4*)&x[(size_t)t * Dm + tid * 4];
  float ss = v.x * v.x + v.y * v.y + v.z * v.z + v.w * v.w;
  for (int o = 32; o > 0; o >>= 1) ss += __shfl_down(ss, o);
  __shared__ float sred[4];
  if ((tid & 63) == 0) sred[tid >> 6] = ss;
  __syncthreads();
  float tot = sred[0] + sred[1] + sred[2] + sred[3];
  float rms = rsqrtf(tot * (1.f / Dm) + 1e-6f);
  float4 w4 = *(const float4*)&w[tid * 4];
  float4 o4;
  o4.x = v.x * rms * w4.x; o4.y = v.y * rms * w4.y;
  o4.z = v.z * rms * w4.z; o4.w = v.w * rms * w4.w;
  *(float4*)&out[(size_t)t * Dm + tid * 4] = o4;
}

// ---------------------------------------------------------------------------
// fp32 GEMM: C[M,N] = A[M,K] @ B[K,N]  (+epilogues). 128x128 tile, 8x8/thread.
// EPI 0: C = AB ; EPI 1: C = AB + bias ; EPI 2: C += AB, out2 = resid + C
template <int EPI>
__global__ __launch_bounds__(256) void gemm_f32(const float* __restrict__ A,
                                                const float* __restrict__ B,
                                                float* __restrict__ C,
                                                int M, int N, int K,
                                                const float* __restrict__ bias,
                                                const float* __restrict__ resid,
                                                float* __restrict__ out2) {
  __shared__ float As[16][132];  // transposed A tile, padded
  __shared__ float Bs[16][132];
  const int tid = threadIdx.x;
  const int tx = tid & 15, ty = tid >> 4;
  const int m0 = blockIdx.y * 128, n0 = blockIdx.x * 128;
  float acc[8][8];
  #pragma unroll
  for (int i = 0; i < 8; ++i) {
    #pragma unroll
    for (int j = 0; j < 8; ++j) acc[i][j] = 0.f;
  }
  for (int k0 = 0; k0 < K; k0 += 16) {
    #pragma unroll
    for (int i = 0; i < 2; ++i) {
      int idx = tid + 256 * i;
      int r = idx >> 2, kq = idx & 3;
      float4 v = *(const float4*)&A[(size_t)(m0 + r) * K + k0 + kq * 4];
      As[kq * 4 + 0][r] = v.x; As[kq * 4 + 1][r] = v.y;
      As[kq * 4 + 2][r] = v.z; As[kq * 4 + 3][r] = v.w;
    }
    #pragma unroll
    for (int i = 0; i < 2; ++i) {
      int idx = tid + 256 * i;
      int kr = idx >> 5, nq = idx & 31;
      *(float4*)&Bs[kr][nq * 4] = *(const float4*)&B[(size_t)(k0 + kr) * N + n0 + nq * 4];
    }
    __syncthreads();
    #pragma unroll
    for (int kk = 0; kk < 16; ++kk) {
      float a[8], b[8];
      *(float4*)&a[0] = *(const float4*)&As[kk][ty * 8];
      *(float4*)&a[4] = *(const float4*)&As[kk][ty * 8 + 4];
      *(float4*)&b[0] = *(const float4*)&Bs[kk][tx * 8];
      *(float4*)&b[4] = *(const float4*)&Bs[kk][tx * 8 + 4];
      #pragma unroll
      for (int i = 0; i < 8; ++i) {
        #pragma unroll
        for (int j = 0; j < 8; ++j) acc[i][j] = fmaf(a[i], b[j], acc[i][j]);
      }
    }
    __syncthreads();
  }
  float4 b0, b1;
  if constexpr (EPI == 1) {
    b0 = *(const float4*)&bias[n0 + tx * 8];
    b1 = *(const float4*)&bias[n0 + tx * 8 + 4];
  }
  #pragma unroll
  for (int i = 0; i < 8; ++i) {
    int row = m0 + ty * 8 + i;
    size_t base = (size_t)row * N + n0 + tx * 8;
    float4 v0, v1;
    v0.x = acc[i][0]; v0.y = acc[i][1]; v0.z = acc[i][2]; v0.w = acc[i][3];
    v1.x = acc[i][4]; v1.y = acc[i][5]; v1.z = acc[i][6]; v1.w = acc[i][7];
    if constexpr (EPI == 0) {
      *(float4*)&C[base] = v0; *(float4*)&C[base + 4] = v1;
    } else if constexpr (EPI == 1) {
      v0.x += b0.x; v0.y += b0.y; v0.z += b0.z; v0.w += b0.w;
      v1.x += b1.x; v1.y += b1.y; v1.z += b1.z; v1.w += b1.w;
      *(float4*)&C[base] = v0; *(float4*)&C[base + 4] = v1;
    } else {
      float4 c0 = *(const float4*)&C[base];
      float4 c1 = *(const float4*)&C[base + 4];
      v0.x += c0.x; v0.y += c0.y; v0.z += c0.z; v0.w += c0.w;
      v1.x += c1.x; v1.y += c1.y; v1.z += c1.z; v1.w += c1.w;
      *(float4*)&C[base] = v0; *(float4*)&C[base + 4] = v1;
      float4 r0 = *(const float4*)&resid[base];
      float4 r1 = *(const float4*)&resid[base + 4];
      float4 o0, o1;
      o0.x = r0.x + v0.x; o0.y = r0.y + v0.y; o0.z = r0.z + v0.z; o0.w = r0.w + v0.w;
      o1.x = r1.x + v1.x; o1.y = r1.y + v1.y; o1.z = r1.z + v1.z; o1.w = r1.w + v1.w;
      *(float4*)&out2[base] = o0; *(float4*)&out2[base + 4] = o1;
    }
  }
}

// ---------------------------------------------------------------------------
// fp32 flash attention, GQA 16 Q-heads / 4 KV-heads, HD=64, non-causal.
// Block = (q-tile of 64 rows) x (one b,h). Threads: 64 rows x 4 lanes.
__global__ __launch_bounds__(256) void attn_f32(const float* __restrict__ qf,
                                                const float* __restrict__ kf,
                                                const float* __restrict__ vf,
                                                float* __restrict__ attnf) {
  __shared__ float Qs[64][68];
  __shared__ float KPs[64][68];  // K tile, reused as P tile
  __shared__ float Vs[64][68];
  const int bh = blockIdx.y;
  const int b = bh >> 4, h = bh & 15, kvh = h >> 2;
  const int qt = blockIdx.x;
  const int tid = threadIdx.x;
  const int r = tid >> 2, qd = tid & 3;
  {
    int row = tid >> 4, d4 = tid & 15;
    #pragma unroll
    for (int rep = 0; rep < 4; ++rep) {
      int rr = row + rep * 16;
      *(float4*)&Qs[rr][d4 * 4] =
          *(const float4*)&qf[((size_t)(b * Ss + qt * 64 + rr)) * Dm + h * 64 + d4 * 4];
    }
  }
  float m = -1e30f, l = 0.f;
  float acc[16];
  #pragma unroll
  for (int i = 0; i < 16; ++i) acc[i] = 0.f;

  for (int kt = 0; kt < 16; ++kt) {
    __syncthreads();  // prior tile's reads done (also publishes Qs on iter 0)
    {
      int row = tid >> 4, d4 = tid & 15;
      #pragma unroll
      for (int rep = 0; rep < 4; ++rep) {
        int rr = row + rep * 16;
        size_t g = ((size_t)(b * Ss + kt * 64 + rr)) * 256 + kvh * 64 + d4 * 4;
        *(float4*)&KPs[rr][d4 * 4] = *(const float4*)&kf[g];
        *(float4*)&Vs[rr][d4 * 4]  = *(const float4*)&vf[g];
      }
    }
    __syncthreads();
    float s[16];
    #pragma unroll
    for (int jj = 0; jj < 16; ++jj) s[jj] = 0.f;
    for (int d4 = 0; d4 < 16; ++d4) {
      float4 q4 = *(const float4*)&Qs[r][d4 * 4];
      #pragma unroll
      for (int jj = 0; jj < 16; ++jj) {
        float4 k4 = *(const float4*)&KPs[qd + 4 * jj][d4 * 4];
        s[jj] += q4.x * k4.x + q4.y * k4.y + q4.z * k4.z + q4.w * k4.w;
      }
    }
    float mt = -1e30f;
    #pragma unroll
    for (int jj = 0; jj < 16; ++jj) { s[jj] *= 0.125f; mt = fmaxf(mt, s[jj]); }
    mt = fmaxf(mt, __shfl_xor(mt, 1));
    mt = fmaxf(mt, __shfl_xor(mt, 2));
    float mnew = fmaxf(m, mt);
    float scale = expf(m - mnew);
    float lsum = 0.f;
    #pragma unroll
    for (int jj = 0; jj < 16; ++jj) { float p = expf(s[jj] - mnew); s[jj] = p; lsum += p; }
    lsum += __shfl_xor(lsum, 1);
    lsum += __shfl_xor(lsum, 2);
    l = l * scale + lsum;
    m = mnew;
    #pragma unroll
    for (int i = 0; i < 16; ++i) acc[i] *= scale;
    __syncthreads();  // everyone done reading K before P overwrite
    #pragma unroll
    for (int jj = 0; jj < 16; ++jj) KPs[r][qd + 4 * jj] = s[jj];
    __syncthreads();
    for (int j = 0; j < 64; ++j) {
      float p = KPs[r][j];
      #pragma unroll
      for (int d4 = 0; d4 < 4; ++d4) {
        float4 v4 = *(const float4*)&Vs[j][qd * 16 + d4 * 4];
        acc[d4 * 4 + 0] = fmaf(p, v4.x, acc[d4 * 4 + 0]);
        acc[d4 * 4 + 1] = fmaf(p, v4.y, acc[d4 * 4 + 1]);
        acc[d4 * 4 + 2] = fmaf(p, v4.z, acc[d4 * 4 + 2]);
        acc[d4 * 4 + 3] = fmaf(p, v4.w, acc[d4 * 4 + 3]);
      }
    }
  }
  float inv = 1.f / l;
  size_t o = ((size_t)(b * Ss + qt * 64 + r)) * Dm + h * 64 + qd * 16;
  #pragma unroll
  for (int i = 0; i < 16; i += 4) {
    float4 v;
    v.x = acc[i] * inv; v.y = acc[i + 1] * inv; v.z = acc[i + 2] * inv; v.w = acc[i + 3] * inv;
    *(float4*)&attnf[o + i] = v;
  }
}

// ---------------------------------------------------------------------------
// RMSNorm #2 + fp32 gate + top-2 selection + expert list build (+ h2 bf16)
__global__ __launch_bounds__(256) void rms2_gate(const float* __restrict__ h,
                                                 const float* __restrict__ ln2w,
                                                 const float* __restrict__ gatew,
                                                 unsigned short* __restrict__ h2b,
                                                 int* __restrict__ cnt,
                                                 int* __restrict__ ltok,
                                                 float* __restrict__ lw) {
  const int t = blockIdx.x, tid = threadIdx.x;
  float4 hv = *(const float4*)&h[(size_t)t * Dm + tid * 4];
  float ss = hv.x * hv.x + hv.y * hv.y + hv.z * hv.z + hv.w * hv.w;
  for (int o = 32; o > 0; o >>= 1) ss += __shfl_down(ss, o);
  __shared__ float sred[4];
  __shared__ float slog[4][8];
  if ((tid & 63) == 0) sred[tid >> 6] = ss;
  __syncthreads();
  float tot = sred[0] + sred[1] + sred[2] + sred[3];
  float rms = rsqrtf(tot * (1.f / Dm) + 1e-6f);
  float4 w4 = *(const float4*)&ln2w[tid * 4];
  float x0 = hv.x * rms * w4.x, x1 = hv.y * rms * w4.y;
  float x2 = hv.z * rms * w4.z, x3 = hv.w * rms * w4.w;
  unsigned int p0 = (unsigned)f2bf(x0) | ((unsigned)f2bf(x1) << 16);
  unsigned int p1 = (unsigned)f2bf(x2) | ((unsigned)f2bf(x3) << 16);
  uint2 pk; pk.x = p0; pk.y = p1;
  *(uint2*)&h2b[(size_t)t * Dm + tid * 4] = pk;
  // fp32 gate partials (exact top-k decision path)
  float pe[8];
  #pragma unroll
  for (int e = 0; e < 8; ++e) pe[e] = 0.f;
  const int d = tid * 4;
  float xv[4] = {x0, x1, x2, x3};
  #pragma unroll
  for (int i = 0; i < 4; ++i) {
    const float* gr = &gatew[(size_t)(d + i) * 8];
    float4 g0 = *(const float4*)gr;
    float4 g1 = *(const float4*)(gr + 4);
    pe[0] = fmaf(xv[i], g0.x, pe[0]); pe[1] = fmaf(xv[i], g0.y, pe[1]);
    pe[2] = fmaf(xv[i], g0.z, pe[2]); pe[3] = fmaf(xv[i], g0.w, pe[3]);
    pe[4] = fmaf(xv[i], g1.x, pe[4]); pe[5] = fmaf(xv[i], g1.y, pe[5]);
    pe[6] = fmaf(xv[i], g1.z, pe[6]); pe[7] = fmaf(xv[i], g1.w, pe[7]);
  }
  #pragma unroll
  for (int e = 0; e < 8; ++e) {
    float v = pe[e];
    for (int o = 32; o > 0; o >>= 1) v += __shfl_down(v, o);
    if ((tid & 63) == 0) slog[tid >> 6][e] = v;
  }
  __syncthreads();
  if (tid == 0) {
    float lg[8];
    #pragma unroll
    for (int e = 0; e < 8; ++e) lg[e] = slog[0][e] + slog[1][e] + slog[2][e] + slog[3][e];
    int e1 = 0;
    for (int e = 1; e < 8; ++e) if (lg[e] > lg[e1]) e1 = e;
    int e2 = (e1 == 0) ? 1 : 0;
    for (int e = 0; e < 8; ++e) if (e != e1 && lg[e] > lg[e2]) e2 = e;
    float mx = lg[e1];
    float ex1 = expf(lg[e1] - mx), ex2 = expf(lg[e2] - mx);
    float inv = 1.f / (ex1 + ex2);
    int i1 = atomicAdd(&cnt[e1], 1);
    ltok[e1 * Tn + i1] = t; lw[e1 * Tn + i1] = ex1 * inv;
    int i2 = atomicAdd(&cnt[e2], 1);
    ltok[e2 * Tn + i2] = t; lw[e2 * Tn + i2] = ex2 * inv;
  }
}

__global__ void excl_scan(const int* __restrict__ cnt, int* __restrict__ offs) {
  if (threadIdx.x == 0) {
    int o = 0;
    for (int e = 0; e < 8; ++e) { offs[e] = o; o += cnt[e]; }
  }
}

// ---------------------------------------------------------------------------
// fp32 [R][C] -> bf16 [C][R] transpose+convert (batched over blockIdx.z)
__global__ __launch_bounds__(256) void conv_transpose_bf16(const float* __restrict__ in,
                                                           unsigned short* __restrict__ out,
                                                           int R, int C) {
  __shared__ float tile[32][33];
  const float* src = in + (size_t)blockIdx.z * R * C;
  unsigned short* dst = out + (size_t)blockIdx.z * R * C;
  const int c0 = blockIdx.x * 32, r0 = blockIdx.y * 32;
  const int tx = threadIdx.x & 31, ty = threadIdx.x >> 5;
  #pragma unroll
  for (int i = 0; i < 4; ++i)
    tile[ty + 8 * i][tx] = src[(size_t)(r0 + ty + 8 * i) * C + c0 + tx];
  __syncthreads();
  #pragma unroll
  for (int i = 0; i < 4; ++i)
    dst[(size_t)(c0 + ty + 8 * i) * R + r0 + tx] = f2bf(tile[tx][ty + 8 * i]);
}

// ---------------------------------------------------------------------------
// MoE stage 1: act = silu(Xg @ w1[e]) * (Xg @ w3[e]), Xg = gathered h2 (bf16)
// Block tile 128(tokens) x 64(FF), dual-B, 4 waves (2x2), mfma 16x16x32 bf16.
__global__ __launch_bounds__(256) void moe_stage1(const unsigned short* __restrict__ h2b,
                                                  const unsigned short* __restrict__ w1t,
                                                  const unsigned short* __restrict__ w3t,
                                                  const int* __restrict__ cnt,
                                                  const int* __restrict__ offs,
                                                  const int* __restrict__ ltok,
                                                  unsigned short* __restrict__ act) {
  const int e = blockIdx.z;
  const int cntE = cnt[e];
  const int m0 = blockIdx.y * 128;
  if (m0 >= cntE) return;
  const int n0 = blockIdx.x * 64;
  const int offsE = offs[e];
  const int tid = threadIdx.x;
  const int wv = tid >> 6, lane = tid & 63;
  const int wm = wv >> 1, wn = wv & 1;

  __shared__ unsigned short As[128 * 40];   // [row][32k] pad->40 shorts/row
  __shared__ unsigned short B1s[64 * 40];
  __shared__ unsigned short B3s[64 * 40];

  f32x4 acc1[4][2], acc3[4][2];
  #pragma unroll
  for (int i = 0; i < 4; ++i) {
    #pragma unroll
    for (int j = 0; j < 2; ++j) {
      acc1[i][j] = (f32x4){0.f, 0.f, 0.f, 0.f};
      acc3[i][j] = (f32x4){0.f, 0.f, 0.f, 0.f};
    }
  }
  const int rlo = lane >> 2, ch = lane & 3;
  const unsigned short* gA[2];
  #pragma unroll
  for (int p = 0; p < 2; ++p) {
    int row = p * 64 + wv * 16 + rlo;
    int ri = (m0 + row < cntE) ? (m0 + row) : 0;
    int tok = ltok[e * Tn + ri];
    gA[p] = h2b + (size_t)tok * Dm + ch * 8;
  }
  const unsigned short* gB1 = w1t + ((size_t)e * FFf + n0 + wv * 16 + rlo) * Dm + ch * 8;
  const unsigned short* gB3 = w3t + ((size_t)e * FFf + n0 + wv * 16 + rlo) * Dm + ch * 8;
  const int lwA0 = (wv * 16 + rlo) * 40 + ch * 8;
  const int lwA1 = (64 + wv * 16 + rlo) * 40 + ch * 8;
  const int lwB  = (wv * 16 + rlo) * 40 + ch * 8;
  int roA[4], roB[2];
  #pragma unroll
  for (int mf = 0; mf < 4; ++mf) roA[mf] = (wm * 64 + mf * 16 + (lane & 15)) * 40 + (lane >> 4) * 8;
  #pragma unroll
  for (int nf = 0; nf < 2; ++nf) roB[nf] = (wn * 32 + nf * 16 + (lane & 15)) * 40 + (lane >> 4) * 8;

  int4v ra0 = *(const int4v*)(gA[0]);
  int4v ra1 = *(const int4v*)(gA[1]);
  int4v rb1 = *(const int4v*)(gB1);
  int4v rb3 = *(const int4v*)(gB3);

  constexpr int NT = Dm / 32;
  for (int kt = 0; kt < NT; ++kt) {
    __syncthreads();
    *(int4v*)&As[lwA0] = ra0;
    *(int4v*)&As[lwA1] = ra1;
    *(int4v*)&B1s[lwB] = rb1;
    *(int4v*)&B3s[lwB] = rb3;
    __syncthreads();
    if (kt + 1 < NT) {
      int ko = (kt + 1) * 32;
      ra0 = *(const int4v*)(gA[0] + ko);
      ra1 = *(const int4v*)(gA[1] + ko);
      rb1 = *(const int4v*)(gB1 + ko);
      rb3 = *(const int4v*)(gB3 + ko);
    }
    short8 a[4], b1f[2], b3f[2];
    #pragma unroll
    for (int mf = 0; mf < 4; ++mf) a[mf] = *(const short8*)&As[roA[mf]];
    #pragma unroll
    for (int nf = 0; nf < 2; ++nf) {
      b1f[nf] = *(const short8*)&B1s[roB[nf]];
      b3f[nf] = *(const short8*)&B3s[roB[nf]];
    }
    #pragma unroll
    for (int mf = 0; mf < 4; ++mf) {
      #pragma unroll
      for (int nf = 0; nf < 2; ++nf) {
        acc1[mf][nf] = __builtin_amdgcn_mfma_f32_16x16x32_bf16(a[mf], b1f[nf], acc1[mf][nf], 0, 0, 0);
        acc3[mf][nf] = __builtin_amdgcn_mfma_f32_16x16x32_bf16(a[mf], b3f[nf], acc3[mf][nf], 0, 0, 0);
      }
    }
  }
  const int rbase = (lane >> 4) * 4, ccol = lane & 15;
  #pragma unroll
  for (int mf = 0; mf < 4; ++mf) {
    #pragma unroll
    for (int rg = 0; rg < 4; ++rg) {
      int mrow = wm * 64 + mf * 16 + rbase + rg;
      if (m0 + mrow < cntE) {
        size_t arow = (size_t)(offsE + m0 + mrow) * FFf;
        #pragma unroll
        for (int nf = 0; nf < 2; ++nf) {
          float h1 = acc1[mf][nf][rg];
          float h3 = acc3[mf][nf][rg];
          float sv = h1 / (1.f + __expf(-h1)) * h3;
          act[arow + n0 + wn * 32 + nf * 16 + ccol] = f2bf(sv);
        }
      }
    }
  }
}

// ---------------------------------------------------------------------------
// MoE stage 2: h[tok,:] += w_pair * (act_row @ w2[e]).  Tile 128x128.
__global__ __launch_bounds__(256) void moe_stage2(const unsigned short* __restrict__ act,
                                                  const unsigned short* __restrict__ w2t,
                                                  const int* __restrict__ cnt,
                                                  const int* __restrict__ offs,
                                                  const int* __restrict__ ltok,
                                                  const float* __restrict__ lw,
                                                  float* __restrict__ hout) {
  const int e = blockIdx.z;
  const int cntE = cnt[e];
  const int m0 = blockIdx.y * 128;
  if (m0 >= cntE) return;
  const int n0 = blockIdx.x * 128;
  const int offsE = offs[e];
  const int tid = threadIdx.x;
  const int wv = tid >> 6, lane = tid & 63;
  const int wm = wv >> 1, wn = wv & 1;

  __shared__ unsigned short As[128 * 40];
  __shared__ unsigned short Bs[128 * 40];

  f32x4 acc[4][4];
  #pragma unroll
  for (int i = 0; i < 4; ++i) {
    #pragma unroll
    for (int j = 0; j < 4; ++j) acc[i][j] = (f32x4){0.f, 0.f, 0.f, 0.f};
  }
  const int rlo = lane >> 2, ch = lane & 3;
  const unsigned short* gA[2];
  const unsigned short* gB[2];
  int lwA[2], lwBo[2];
  #pragma unroll
  for (int p = 0; p < 2; ++p) {
    int row = p * 64 + wv * 16 + rlo;
    int ri = (m0 + row < cntE) ? (m0 + row) : 0;
    gA[p] = act + (size_t)(offsE + ri) * FFf + ch * 8;
    gB[p] = w2t + ((size_t)e * Dm + n0 + row) * FFf + ch * 8;
    lwA[p] = row * 40 + ch * 8;
    lwBo[p] = row * 40 + ch * 8;
  }
  int roA[4], roB[4];
  #pragma unroll
  for (int mf = 0; mf < 4; ++mf) roA[mf] = (wm * 64 + mf * 16 + (lane & 15)) * 40 + (lane >> 4) * 8;
  #pragma unroll
  for (int nf = 0; nf < 4; ++nf) roB[nf] = (wn * 64 + nf * 16 + (lane & 15)) * 40 + (lane >> 4) * 8;

  int4v ra0 = *(const int4v*)(gA[0]);
  int4v ra1 = *(const int4v*)(gA[1]);
  int4v rb0 = *(const int4v*)(gB[0]);
  int4v rb1 = *(const int4v*)(gB[1]);

  constexpr int NT = FFf / 32;  // 88
  for (int kt = 0; kt < NT; ++kt) {
    __syncthreads();
    *(int4v*)&As[lwA[0]] = ra0;
    *(int4v*)&As[lwA[1]] = ra1;
    *(int4v*)&Bs[lwBo[0]] = rb0;
    *(int4v*)&Bs[lwBo[1]] = rb1;
    __syncthreads();
    if (kt + 1 < NT) {
      int ko = (kt + 1) * 32;
      ra0 = *(const int4v*)(gA[0] + ko);
      ra1 = *(const int4v*)(gA[1] + ko);
      rb0 = *(const int4v*)(gB[0] + ko);
      rb1 = *(const int4v*)(gB[1] + ko);
    }
    short8 a[4], b[4];
    #pragma unroll
    for (int mf = 0; mf < 4; ++mf) a[mf] = *(const short8*)&As[roA[mf]];
    #pragma unroll
    for (int nf = 0; nf < 4; ++nf) b[nf] = *(const short8*)&Bs[roB[nf]];
    #pragma unroll
    for (int mf = 0; mf < 4; ++mf) {
      #pragma unroll
      for (int nf = 0; nf < 4; ++nf)
        acc[mf][nf] = __builtin_amdgcn_mfma_f32_16x16x32_bf16(a[mf], b[nf], acc[mf][nf], 0, 0, 0);
    }
  }
  const int rbase = (lane >> 4) * 4, ccol = lane & 15;
  #pragma unroll
  for (int mf = 0; mf < 4; ++mf) {
    #pragma unroll
    for (int rg = 0; rg < 4; ++rg) {
      int prow = m0 + wm * 64 + mf * 16 + rbase + rg;
      if (prow < cntE) {
        int tok = ltok[e * Tn + prow];
        float w = lw[e * Tn + prow];
        #pragma unroll
        for (int nf = 0; nf < 4; ++nf) {
          atomicAdd(&hout[(size_t)tok * Dm + n0 + wn * 64 + nf * 16 + ccol],
                    w * acc[mf][nf][rg]);
        }
      }
    }
  }
}

// ---------------------------------------------------------------------------
extern "C" void kernel_launch(void* const* d_in, const int* in_sizes, int n_in,
                              void* d_out, int out_size, void* d_ws, size_t ws_size,
                              hipStream_t stream) {
  const float* hidden = (const float*)d_in[0];
  // d_in[1] = position_ids (unused by the reference computation)
  const float* prev  = (const float*)d_in[2];
  const float* wq    = (const float*)d_in[3];
  const float* wk    = (const float*)d_in[4];
  const float* wv    = (const float*)d_in[5];
  const float* wo    = (const float*)d_in[6];
  const float* mixw  = (const float*)d_in[7];
  const float* mixb  = (const float*)d_in[8];
  const float* gatew = (const float*)d_in[9];
  const float* w1    = (const float*)d_in[10];
  const float* w2    = (const float*)d_in[11];
  const float* w3    = (const float*)d_in[12];
  const float* ln1   = (const float*)d_in[13];
  const float* ln2   = (const float*)d_in[14];
  const float* compw = (const float*)d_in[15];
  const float* compb = (const float*)d_in[16];

  float* out_h    = (float*)d_out;
  float* out_mix  = out_h + 4194304;
  float* out_comp = out_h + 8388608;

  // ---- workspace layout (bytes) ----
  constexpr size_t SZ_WT  = (size_t)Ee * FFf * Dm * 2;          // 46,137,344
  constexpr size_t O_W1T  = 0;
  constexpr size_t O_W3T  = O_W1T + SZ_WT;
  constexpr size_t O_W2T  = O_W3T + SZ_WT;
  constexpr size_t O_CNT  = O_W2T + SZ_WT;                       // 32 B
  constexpr size_t O_OFF  = O_CNT + 64;
  constexpr size_t O_LTOK = O_CNT + 128;                         // 8*4096*4
  constexpr size_t O_LW   = O_LTOK + 131072;
  constexpr size_t O_SCR  = O_CNT + 262400;                      // 256-aligned
  constexpr size_t O_QF   = O_SCR;               // fp32 q   (alias: h2b later)
  constexpr size_t O_KF   = O_SCR + 16777216;    // fp32 k
  constexpr size_t O_VF   = O_SCR + 20971520;    // fp32 v
  constexpr size_t O_ATT  = O_SCR + 25165824;    // fp32 attn out (alias: xf earlier)
  constexpr size_t O_CUR  = O_SCR + 41943040;    // fp32 wo out
  constexpr size_t O_ACT  = O_SCR + 8388608;     // bf16 act [8192][2816] (aliases dead bufs)
  constexpr size_t WS_NEED = O_SCR + 58720256;   // 197,394,688 B

  if (ws_size < WS_NEED || out_size < 9437184 || n_in < 17 ||
      in_sizes[0] != 4194304 || in_sizes[10] != 23068672 || in_sizes[7] != 2097152) {
    fprintf(stderr,
            "kernel_launch: precondition failed ws_size=%zu need=%zu out=%d n_in=%d "
            "(in0=%d in7=%d in10=%d)\n",
            ws_size, WS_NEED, out_size, n_in, in_sizes[0], in_sizes[7], in_sizes[10]);
    return;
  }

  char* ws = (char*)d_ws;
  unsigned short* w1t  = (unsigned short*)(ws + O_W1T);
  unsigned short* w3t  = (unsigned short*)(ws + O_W3T);
  unsigned short* w2t  = (unsigned short*)(ws + O_W2T);
  int*   cnt  = (int*)(ws + O_CNT);
  int*   offs = (int*)(ws + O_OFF);
  int*   ltok = (int*)(ws + O_LTOK);
  float* lwgt = (float*)(ws + O_LW);
  float* qf    = (float*)(ws + O_QF);
  float* kfb   = (float*)(ws + O_KF);
  float* vfb   = (float*)(ws + O_VF);
  float* attnf = (float*)(ws + O_ATT);
  float* xf    = (float*)(ws + O_ATT);   // alias: dead before attnf written
  float* curf  = (float*)(ws + O_CUR);
  unsigned short* h2b = (unsigned short*)(ws + O_QF);  // alias: qf dead by then
  unsigned short* act = (unsigned short*)(ws + O_ACT);

  hipMemsetAsync(cnt, 0, 8 * sizeof(int), stream);

  // weight convert+transpose to bf16 [N][K] (MoE only)
  conv_transpose_bf16<<<dim3(88, 32, 8), 256, 0, stream>>>(w1, w1t, 1024, 2816);
  conv_transpose_bf16<<<dim3(88, 32, 8), 256, 0, stream>>>(w3, w3t, 1024, 2816);
  conv_transpose_bf16<<<dim3(32, 88, 8), 256, 0, stream>>>(w2, w2t, 2816, 1024);

  // pre-gate path, exact fp32
  rms1_kernel<<<Tn, 256, 0, stream>>>(hidden, ln1, xf);
  gemm_f32<0><<<dim3(8, 32), 256, 0, stream>>>(xf, wq, qf, Tn, 1024, 1024, nullptr, nullptr, nullptr);
  gemm_f32<0><<<dim3(2, 32), 256, 0, stream>>>(xf, wk, kfb, Tn, 256, 1024, nullptr, nullptr, nullptr);
  gemm_f32<0><<<dim3(2, 32), 256, 0, stream>>>(xf, wv, vfb, Tn, 256, 1024, nullptr, nullptr, nullptr);
  attn_f32<<<dim3(16, 64), 256, 0, stream>>>(qf, kfb, vfb, attnf);
  gemm_f32<0><<<dim3(8, 32), 256, 0, stream>>>(attnf, wo, curf, Tn, 1024, 1024, nullptr, nullptr, nullptr);
  // mixed = cur@mixTop + bias ; then += prev@mixBot, h = hidden + mixed
  gemm_f32<1><<<dim3(8, 32), 256, 0, stream>>>(curf, mixw, out_mix, Tn, 1024, 1024, mixb, nullptr, nullptr);
  gemm_f32<2><<<dim3(8, 32), 256, 0, stream>>>(prev, mixw + 1048576, out_mix, Tn, 1024, 1024,
                                               nullptr, hidden, out_h);
  // gate (fp32 logits, exact top-2) + h2 bf16
  rms2_gate<<<Tn, 256, 0, stream>>>(out_h, ln2, gatew, h2b, cnt, ltok, lwgt);
  excl_scan<<<1, 64, 0, stream>>>(cnt, offs);

  // MoE expert compute, bf16 MFMA, grouped by expert
  moe_stage1<<<dim3(44, 32, 8), 256, 0, stream>>>(h2b, w1t, w3t, cnt, offs, ltok, act);
  moe_stage2<<<dim3(8, 32, 8), 256, 0, stream>>>(act, w2t, cnt, offs, ltok, lwgt, out_h);

  // compression head (after final h)
  gemm_f32<1><<<dim3(2, 32), 256, 0, stream>>>(out_h, compw, out_comp, Tn, 256, 1024,
                                               compb, nullptr, nullptr);
}

// Round 5
// 1160.660 us; speedup vs baseline: 1.7628x; 1.7628x over previous
//
#include <hip/hip_runtime.h>
#include <cstdio>
#include <cstdint>

// ---------------------------------------------------------------------------
// Fused transformer block (B=4,S=1024,D=1024,H=16,KVH=4,E=8,TOPK=2,FF=2816)
// R2 (resubmit R5): split-bf16 (hi+lo, 3-term) MFMA for the whole pre-gate
// path (fp32-class accuracy, flip-safe gating), bf16 MFMA grouped MoE.
// ---------------------------------------------------------------------------

typedef __attribute__((ext_vector_type(4))) int   int4v;
typedef __attribute__((ext_vector_type(8))) short short8;
typedef __attribute__((ext_vector_type(4))) short short4v;
typedef __attribute__((ext_vector_type(4))) float f32x4;

constexpr int Tn  = 4096;   // B*S tokens
constexpr int Dm  = 1024;   // model dim
constexpr int Ss  = 1024;   // seq
constexpr int Ee  = 8;      // experts
constexpr int FFf = 2816;   // expert hidden

__device__ __forceinline__ unsigned short f2bf(float f) {
  union { float f; unsigned u; } v; v.f = f;
  unsigned r = v.u + 0x7FFFu + ((v.u >> 16) & 1u);
  return (unsigned short)(r >> 16);
}
__device__ __forceinline__ float bf2f(unsigned short h) {
  union { unsigned u; float f; } v; v.u = ((unsigned)h) << 16; return v.f;
}
__device__ __forceinline__ void split2(float x, unsigned short& hi, unsigned short& lo) {
  hi = f2bf(x);
  lo = f2bf(x - bf2f(hi));
}

// ---------------------------------------------------------------------------
// RMSNorm #1
__global__ __launch_bounds__(256) void rms1_kernel(const float* __restrict__ x,
                                                   const float* __restrict__ w,
                                                   float* __restrict__ out) {
  const int t = blockIdx.x, tid = threadIdx.x;
  float4 v = *(const float4*)&x[(size_t)t * Dm + tid * 4];
  float ss = v.x * v.x + v.y * v.y + v.z * v.z + v.w * v.w;
  for (int o = 32; o > 0; o >>= 1) ss += __shfl_down(ss, o);
  __shared__ float sred[4];
  if ((tid & 63) == 0) sred[tid >> 6] = ss;
  __syncthreads();
  float tot = sred[0] + sred[1] + sred[2] + sred[3];
  float rms = rsqrtf(tot * (1.f / Dm) + 1e-6f);
  float4 w4 = *(const float4*)&w[tid * 4];
  float4 o4;
  o4.x = v.x * rms * w4.x; o4.y = v.y * rms * w4.y;
  o4.z = v.z * rms * w4.z; o4.w = v.w * rms * w4.w;
  *(float4*)&out[(size_t)t * Dm + tid * 4] = o4;
}

// ---------------------------------------------------------------------------
// fp32 [R][C] -> bf16 hi/lo [C][R]  (transpose + 2-way split)
__global__ __launch_bounds__(256) void split_transpose(const float* __restrict__ in,
                                                       unsigned short* __restrict__ hi,
                                                       unsigned short* __restrict__ lo,
                                                       int R, int C) {
  __shared__ float tile[32][33];
  const int c0 = blockIdx.x * 32, r0 = blockIdx.y * 32;
  const int tx = threadIdx.x & 31, ty = threadIdx.x >> 5;
  #pragma unroll
  for (int i = 0; i < 4; ++i)
    tile[ty + 8 * i][tx] = in[(size_t)(r0 + ty + 8 * i) * C + c0 + tx];
  __syncthreads();
  #pragma unroll
  for (int i = 0; i < 4; ++i) {
    float v = tile[tx][ty + 8 * i];
    unsigned short h, L; split2(v, h, L);
    hi[(size_t)(c0 + ty + 8 * i) * R + r0 + tx] = h;
    lo[(size_t)(c0 + ty + 8 * i) * R + r0 + tx] = L;
  }
}

// fp32 [R][C] -> bf16 [C][R] (single, for MoE weights)
__global__ __launch_bounds__(256) void conv_transpose_bf16(const float* __restrict__ in,
                                                           unsigned short* __restrict__ out,
                                                           int R, int C) {
  __shared__ float tile[32][33];
  const float* src = in + (size_t)blockIdx.z * R * C;
  unsigned short* dst = out + (size_t)blockIdx.z * R * C;
  const int c0 = blockIdx.x * 32, r0 = blockIdx.y * 32;
  const int tx = threadIdx.x & 31, ty = threadIdx.x >> 5;
  #pragma unroll
  for (int i = 0; i < 4; ++i)
    tile[ty + 8 * i][tx] = src[(size_t)(r0 + ty + 8 * i) * C + c0 + tx];
  __syncthreads();
  #pragma unroll
  for (int i = 0; i < 4; ++i)
    dst[(size_t)(c0 + ty + 8 * i) * R + r0 + tx] = f2bf(tile[tx][ty + 8 * i]);
}

// ---------------------------------------------------------------------------
// Split-bf16 3-term GEMM: C[M,N] = A[M,K](fp32) @ B(hi/lo [N][K] bf16)
// 128x128 tile, KSTEP 32, 4 waves (2x2), 4x4 16x16x32-MFMA frags per wave.
// DUAL: A covers k<1024, A2 covers k>=1024 (both stride lda).
// EPI 0: C = AB ; 1: C = AB+bias ; 2: C = AB+bias, out2 = resid + C
template <int DUAL, int EPI>
__global__ __launch_bounds__(256) void gemm_split3(
    const float* __restrict__ A, const float* __restrict__ A2,
    const unsigned short* __restrict__ Bhi, const unsigned short* __restrict__ Blo,
    float* __restrict__ C, int M, int N, int K, int lda,
    const float* __restrict__ bias, const float* __restrict__ resid,
    float* __restrict__ out2) {
  __shared__ unsigned short Ah[128 * 40], Al[128 * 40];
  __shared__ unsigned short Bh[128 * 40], Bl[128 * 40];
  const int tid = threadIdx.x;
  const int wv = tid >> 6, lane = tid & 63;
  const int wm = wv >> 1, wn = wv & 1;
  const int lg = lane >> 4, lr = lane & 15;
  const int m0 = blockIdx.y * 128, n0 = blockIdx.x * 128;
  f32x4 acc[4][4];
  #pragma unroll
  for (int i = 0; i < 4; ++i)
    #pragma unroll
    for (int j = 0; j < 4; ++j) acc[i][j] = (f32x4){0.f, 0.f, 0.f, 0.f};

  float4 ra[4];
  int4v rbh[2], rbl[2];
  auto loadA = [&](int k0) {
    #pragma unroll
    for (int rep = 0; rep < 4; ++rep) {
      int idx = tid + 256 * rep;
      int row = idx >> 3, f4 = idx & 7;
      int col = k0 + f4 * 4;
      const float* s;
      if (DUAL && col >= 1024) s = &A2[(size_t)(m0 + row) * lda + (col - 1024)];
      else                     s = &A[(size_t)(m0 + row) * lda + col];
      ra[rep] = *(const float4*)s;
    }
  };
  auto loadB = [&](int k0) {
    #pragma unroll
    for (int rep = 0; rep < 2; ++rep) {
      int idx = tid + 256 * rep;
      int n = idx >> 2, c8 = idx & 3;
      rbh[rep] = *(const int4v*)&Bhi[(size_t)(n0 + n) * K + k0 + c8 * 8];
      rbl[rep] = *(const int4v*)&Blo[(size_t)(n0 + n) * K + k0 + c8 * 8];
    }
  };
  loadA(0); loadB(0);
  const int NT = K >> 5;
  for (int kt = 0; kt < NT; ++kt) {
    __syncthreads();
    #pragma unroll
    for (int rep = 0; rep < 4; ++rep) {
      int idx = tid + 256 * rep;
      int row = idx >> 3, f4 = idx & 7;
      unsigned short h0, l0, h1, l1, h2, l2, h3, l3;
      split2(ra[rep].x, h0, l0); split2(ra[rep].y, h1, l1);
      split2(ra[rep].z, h2, l2); split2(ra[rep].w, h3, l3);
      *(short4v*)&Ah[row * 40 + f4 * 4] = (short4v){(short)h0, (short)h1, (short)h2, (short)h3};
      *(short4v*)&Al[row * 40 + f4 * 4] = (short4v){(short)l0, (short)l1, (short)l2, (short)l3};
    }
    #pragma unroll
    for (int rep = 0; rep < 2; ++rep) {
      int idx = tid + 256 * rep;
      int n = idx >> 2, c8 = idx & 3;
      *(int4v*)&Bh[n * 40 + c8 * 8] = rbh[rep];
      *(int4v*)&Bl[n * 40 + c8 * 8] = rbl[rep];
    }
    __syncthreads();
    if (kt + 1 < NT) { loadA((kt + 1) * 32); loadB((kt + 1) * 32); }
    short8 ah[4], al[4], bh[4], bl[4];
    #pragma unroll
    for (int mf = 0; mf < 4; ++mf) {
      ah[mf] = *(const short8*)&Ah[(wm * 64 + mf * 16 + lr) * 40 + lg * 8];
      al[mf] = *(const short8*)&Al[(wm * 64 + mf * 16 + lr) * 40 + lg * 8];
    }
    #pragma unroll
    for (int nf = 0; nf < 4; ++nf) {
      bh[nf] = *(const short8*)&Bh[(wn * 64 + nf * 16 + lr) * 40 + lg * 8];
      bl[nf] = *(const short8*)&Bl[(wn * 64 + nf * 16 + lr) * 40 + lg * 8];
    }
    #pragma unroll
    for (int mf = 0; mf < 4; ++mf)
      #pragma unroll
      for (int nf = 0; nf < 4; ++nf) {
        acc[mf][nf] = __builtin_amdgcn_mfma_f32_16x16x32_bf16(ah[mf], bh[nf], acc[mf][nf], 0, 0, 0);
        acc[mf][nf] = __builtin_amdgcn_mfma_f32_16x16x32_bf16(ah[mf], bl[nf], acc[mf][nf], 0, 0, 0);
        acc[mf][nf] = __builtin_amdgcn_mfma_f32_16x16x32_bf16(al[mf], bh[nf], acc[mf][nf], 0, 0, 0);
      }
  }
  float bv[4];
  if constexpr (EPI >= 1) {
    #pragma unroll
    for (int nf = 0; nf < 4; ++nf) bv[nf] = bias[n0 + wn * 64 + nf * 16 + lr];
  }
  #pragma unroll
  for (int mf = 0; mf < 4; ++mf)
    #pragma unroll
    for (int j = 0; j < 4; ++j) {
      int row = m0 + wm * 64 + mf * 16 + lg * 4 + j;
      size_t rbase = (size_t)row * N + n0 + wn * 64 + lr;
      #pragma unroll
      for (int nf = 0; nf < 4; ++nf) {
        float v = acc[mf][nf][j];
        if constexpr (EPI == 0) {
          C[rbase + nf * 16] = v;
        } else if constexpr (EPI == 1) {
          C[rbase + nf * 16] = v + bv[nf];
        } else {
          float c = v + bv[nf];
          C[rbase + nf * 16] = c;
          out2[rbase + nf * 16] = resid[rbase + nf * 16] + c;
        }
      }
    }
}

// ---------------------------------------------------------------------------
// Split-bf16 MFMA flash attention. GQA 16Q/4KV heads, HD=64, non-causal.
// Block = 64 q-rows x one (b,h); 4 waves, 16 q-rows each; KV tile 64.
__global__ __launch_bounds__(256) void attn_split(const float* __restrict__ qf,
                                                  const float* __restrict__ kf,
                                                  const float* __restrict__ vf,
                                                  float* __restrict__ attnf) {
  __shared__ unsigned short Khi[64][72], Klo[64][72];
  __shared__ unsigned short VThi[64][72], VTlo[64][72];
  __shared__ unsigned short Phi[64][72], Plo[64][72];
  const int bh = blockIdx.y, b = bh >> 4, h = bh & 15, kvh = h >> 2;
  const int qt = blockIdx.x, tid = threadIdx.x;
  const int w = tid >> 6, lane = tid & 63, lg = lane >> 4, lr = lane & 15;

  // Q fragments (held in regs whole kernel). A-frag: row=lr, k=lg*8(+32*ks)
  short8 qh[2], ql[2];
  {
    const float* qp = &qf[((size_t)(b * Ss + qt * 64 + w * 16 + lr)) * Dm + h * 64 + lg * 8];
    #pragma unroll
    for (int ks = 0; ks < 2; ++ks) {
      float4 f0 = *(const float4*)(qp + ks * 32);
      float4 f1 = *(const float4*)(qp + ks * 32 + 4);
      float fv[8] = {f0.x, f0.y, f0.z, f0.w, f1.x, f1.y, f1.z, f1.w};
      #pragma unroll
      for (int j = 0; j < 8; ++j) {
        unsigned short hi, lo; split2(fv[j], hi, lo);
        qh[ks][j] = (short)hi; ql[ks][j] = (short)lo;
      }
    }
  }
  f32x4 o[4];
  #pragma unroll
  for (int i = 0; i < 4; ++i) o[i] = (f32x4){0.f, 0.f, 0.f, 0.f};
  float m[4] = {-1e30f, -1e30f, -1e30f, -1e30f}, l[4] = {0.f, 0.f, 0.f, 0.f};

  for (int kt = 0; kt < 16; ++kt) {
    __syncthreads();
    // K tile: coalesced load, [ks][d] layout, vector LDS writes
    #pragma unroll
    for (int rep = 0; rep < 4; ++rep) {
      int idx = tid + 256 * rep;
      int row = idx >> 4, f4 = (idx & 15) * 4;
      float4 kv = *(const float4*)&kf[((size_t)(b * Ss + kt * 64 + row)) * 256 + kvh * 64 + f4];
      unsigned short h0, l0, h1, l1, h2, l2, h3, l3;
      split2(kv.x, h0, l0); split2(kv.y, h1, l1); split2(kv.z, h2, l2); split2(kv.w, h3, l3);
      *(short4v*)&Khi[row][f4] = (short4v){(short)h0, (short)h1, (short)h2, (short)h3};
      *(short4v*)&Klo[row][f4] = (short4v){(short)l0, (short)l1, (short)l2, (short)l3};
    }
    // V tile: transposed [d][ks] (lane-major rows -> conflict-free b16 writes)
    #pragma unroll
    for (int rep = 0; rep < 4; ++rep) {
      int idx = tid + 256 * rep;
      int row = idx & 63, d4 = (idx >> 6) * 4;
      float4 vv = *(const float4*)&vf[((size_t)(b * Ss + kt * 64 + row)) * 256 + kvh * 64 + d4];
      unsigned short h0, l0, h1, l1, h2, l2, h3, l3;
      split2(vv.x, h0, l0); split2(vv.y, h1, l1); split2(vv.z, h2, l2); split2(vv.w, h3, l3);
      VThi[d4 + 0][row] = h0; VTlo[d4 + 0][row] = l0;
      VThi[d4 + 1][row] = h1; VTlo[d4 + 1][row] = l1;
      VThi[d4 + 2][row] = h2; VTlo[d4 + 2][row] = l2;
      VThi[d4 + 3][row] = h3; VTlo[d4 + 3][row] = l3;
    }
    __syncthreads();
    // scores S[16q][64ks] = Q K^T (3-term split), C-layout: row=lg*4+j, col=nf*16+lr
    f32x4 s[4];
    #pragma unroll
    for (int nf = 0; nf < 4; ++nf) s[nf] = (f32x4){0.f, 0.f, 0.f, 0.f};
    #pragma unroll
    for (int ks = 0; ks < 2; ++ks)
      #pragma unroll
      for (int nf = 0; nf < 4; ++nf) {
        short8 kh = *(const short8*)&Khi[nf * 16 + lr][ks * 32 + lg * 8];
        short8 kl = *(const short8*)&Klo[nf * 16 + lr][ks * 32 + lg * 8];
        s[nf] = __builtin_amdgcn_mfma_f32_16x16x32_bf16(qh[ks], kh, s[nf], 0, 0, 0);
        s[nf] = __builtin_amdgcn_mfma_f32_16x16x32_bf16(qh[ks], kl, s[nf], 0, 0, 0);
        s[nf] = __builtin_amdgcn_mfma_f32_16x16x32_bf16(ql[ks], kh, s[nf], 0, 0, 0);
      }
    #pragma unroll
    for (int nf = 0; nf < 4; ++nf) s[nf] *= 0.125f;
    // online softmax (row stats per reg j, reduce over the 16 lanes of group lg)
    float scl[4];
    #pragma unroll
    for (int j = 0; j < 4; ++j) {
      float v = fmaxf(fmaxf(s[0][j], s[1][j]), fmaxf(s[2][j], s[3][j]));
      v = fmaxf(v, __shfl_xor(v, 1)); v = fmaxf(v, __shfl_xor(v, 2));
      v = fmaxf(v, __shfl_xor(v, 4)); v = fmaxf(v, __shfl_xor(v, 8));
      float mn = fmaxf(m[j], v);
      scl[j] = __expf(m[j] - mn);
      m[j] = mn;
    }
    float sum[4] = {0.f, 0.f, 0.f, 0.f};
    #pragma unroll
    for (int nf = 0; nf < 4; ++nf)
      #pragma unroll
      for (int j = 0; j < 4; ++j) {
        float p = __expf(s[nf][j] - m[j]);
        s[nf][j] = p; sum[j] += p;
      }
    #pragma unroll
    for (int j = 0; j < 4; ++j) {
      float v = sum[j];
      v += __shfl_xor(v, 1); v += __shfl_xor(v, 2);
      v += __shfl_xor(v, 4); v += __shfl_xor(v, 8);
      l[j] = l[j] * scl[j] + v;
    }
    #pragma unroll
    for (int df = 0; df < 4; ++df)
      #pragma unroll
      for (int j = 0; j < 4; ++j) o[df][j] *= scl[j];
    // P split -> LDS (wave-private rows; in-order DS pipe, no barrier needed)
    const int qrow = w * 16 + lg * 4;
    #pragma unroll
    for (int nf = 0; nf < 4; ++nf)
      #pragma unroll
      for (int j = 0; j < 4; ++j) {
        unsigned short hi, lo; split2(s[nf][j], hi, lo);
        Phi[qrow + j][nf * 16 + lr] = hi;
        Plo[qrow + j][nf * 16 + lr] = lo;
      }
    // PV: A=P (row=lr of wave's 16, k=ks), B=V^T (col=d, k=ks)
    #pragma unroll
    for (int ks = 0; ks < 2; ++ks) {
      short8 ph = *(const short8*)&Phi[w * 16 + lr][ks * 32 + lg * 8];
      short8 pl = *(const short8*)&Plo[w * 16 + lr][ks * 32 + lg * 8];
      #pragma unroll
      for (int df = 0; df < 4; ++df) {
        short8 vh = *(const short8*)&VThi[df * 16 + lr][ks * 32 + lg * 8];
        short8 vl = *(const short8*)&VTlo[df * 16 + lr][ks * 32 + lg * 8];
        o[df] = __builtin_amdgcn_mfma_f32_16x16x32_bf16(ph, vh, o[df], 0, 0, 0);
        o[df] = __builtin_amdgcn_mfma_f32_16x16x32_bf16(ph, vl, o[df], 0, 0, 0);
        o[df] = __builtin_amdgcn_mfma_f32_16x16x32_bf16(pl, vh, o[df], 0, 0, 0);
      }
    }
  }
  #pragma unroll
  for (int j = 0; j < 4; ++j) {
    float inv = 1.f / l[j];
    size_t base = ((size_t)(b * Ss + qt * 64 + w * 16 + lg * 4 + j)) * Dm + h * 64 + lr;
    #pragma unroll
    for (int df = 0; df < 4; ++df) attnf[base + df * 16] = o[df][j] * inv;
  }
}

// ---------------------------------------------------------------------------
// RMSNorm #2 + fp32 gate + exact top-2 + expert lists (+ h2 bf16)
__global__ __launch_bounds__(256) void rms2_gate(const float* __restrict__ h,
                                                 const float* __restrict__ ln2w,
                                                 const float* __restrict__ gatew,
                                                 unsigned short* __restrict__ h2b,
                                                 int* __restrict__ cnt,
                                                 int* __restrict__ ltok,
                                                 float* __restrict__ lw) {
  const int t = blockIdx.x, tid = threadIdx.x;
  float4 hv = *(const float4*)&h[(size_t)t * Dm + tid * 4];
  float ss = hv.x * hv.x + hv.y * hv.y + hv.z * hv.z + hv.w * hv.w;
  for (int o = 32; o > 0; o >>= 1) ss += __shfl_down(ss, o);
  __shared__ float sred[4];
  __shared__ float slog[4][8];
  if ((tid & 63) == 0) sred[tid >> 6] = ss;
  __syncthreads();
  float tot = sred[0] + sred[1] + sred[2] + sred[3];
  float rms = rsqrtf(tot * (1.f / Dm) + 1e-6f);
  float4 w4 = *(const float4*)&ln2w[tid * 4];
  float x0 = hv.x * rms * w4.x, x1 = hv.y * rms * w4.y;
  float x2 = hv.z * rms * w4.z, x3 = hv.w * rms * w4.w;
  unsigned int p0 = (unsigned)f2bf(x0) | ((unsigned)f2bf(x1) << 16);
  unsigned int p1 = (unsigned)f2bf(x2) | ((unsigned)f2bf(x3) << 16);
  uint2 pk; pk.x = p0; pk.y = p1;
  *(uint2*)&h2b[(size_t)t * Dm + tid * 4] = pk;
  float pe[8];
  #pragma unroll
  for (int e = 0; e < 8; ++e) pe[e] = 0.f;
  const int d = tid * 4;
  float xv[4] = {x0, x1, x2, x3};
  #pragma unroll
  for (int i = 0; i < 4; ++i) {
    const float* gr = &gatew[(size_t)(d + i) * 8];
    float4 g0 = *(const float4*)gr;
    float4 g1 = *(const float4*)(gr + 4);
    pe[0] = fmaf(xv[i], g0.x, pe[0]); pe[1] = fmaf(xv[i], g0.y, pe[1]);
    pe[2] = fmaf(xv[i], g0.z, pe[2]); pe[3] = fmaf(xv[i], g0.w, pe[3]);
    pe[4] = fmaf(xv[i], g1.x, pe[4]); pe[5] = fmaf(xv[i], g1.y, pe[5]);
    pe[6] = fmaf(xv[i], g1.z, pe[6]); pe[7] = fmaf(xv[i], g1.w, pe[7]);
  }
  #pragma unroll
  for (int e = 0; e < 8; ++e) {
    float v = pe[e];
    for (int o = 32; o > 0; o >>= 1) v += __shfl_down(v, o);
    if ((tid & 63) == 0) slog[tid >> 6][e] = v;
  }
  __syncthreads();
  if (tid == 0) {
    float lg[8];
    #pragma unroll
    for (int e = 0; e < 8; ++e) lg[e] = slog[0][e] + slog[1][e] + slog[2][e] + slog[3][e];
    int e1 = 0;
    for (int e = 1; e < 8; ++e) if (lg[e] > lg[e1]) e1 = e;
    int e2 = (e1 == 0) ? 1 : 0;
    for (int e = 0; e < 8; ++e) if (e != e1 && lg[e] > lg[e2]) e2 = e;
    float mx = lg[e1];
    float ex1 = expf(lg[e1] - mx), ex2 = expf(lg[e2] - mx);
    float inv = 1.f / (ex1 + ex2);
    int i1 = atomicAdd(&cnt[e1], 1);
    ltok[e1 * Tn + i1] = t; lw[e1 * Tn + i1] = ex1 * inv;
    int i2 = atomicAdd(&cnt[e2], 1);
    ltok[e2 * Tn + i2] = t; lw[e2 * Tn + i2] = ex2 * inv;
  }
}

__global__ void excl_scan(const int* __restrict__ cnt, int* __restrict__ offs) {
  if (threadIdx.x == 0) {
    int o = 0;
    for (int e = 0; e < 8; ++e) { offs[e] = o; o += cnt[e]; }
  }
}

// ---------------------------------------------------------------------------
// MoE stage 1
__global__ __launch_bounds__(256) void moe_stage1(const unsigned short* __restrict__ h2b,
                                                  const unsigned short* __restrict__ w1t,
                                                  const unsigned short* __restrict__ w3t,
                                                  const int* __restrict__ cnt,
                                                  const int* __restrict__ offs,
                                                  const int* __restrict__ ltok,
                                                  unsigned short* __restrict__ act) {
  const int e = blockIdx.z;
  const int cntE = cnt[e];
  const int m0 = blockIdx.y * 128;
  if (m0 >= cntE) return;
  const int n0 = blockIdx.x * 64;
  const int offsE = offs[e];
  const int tid = threadIdx.x;
  const int wv = tid >> 6, lane = tid & 63;
  const int wm = wv >> 1, wn = wv & 1;

  __shared__ unsigned short As[128 * 40];
  __shared__ unsigned short B1s[64 * 40];
  __shared__ unsigned short B3s[64 * 40];

  f32x4 acc1[4][2], acc3[4][2];
  #pragma unroll
  for (int i = 0; i < 4; ++i)
    #pragma unroll
    for (int j = 0; j < 2; ++j) {
      acc1[i][j] = (f32x4){0.f, 0.f, 0.f, 0.f};
      acc3[i][j] = (f32x4){0.f, 0.f, 0.f, 0.f};
    }
  const int rlo = lane >> 2, ch = lane & 3;
  const unsigned short* gA[2];
  #pragma unroll
  for (int p = 0; p < 2; ++p) {
    int row = p * 64 + wv * 16 + rlo;
    int ri = (m0 + row < cntE) ? (m0 + row) : 0;
    int tok = ltok[e * Tn + ri];
    gA[p] = h2b + (size_t)tok * Dm + ch * 8;
  }
  const unsigned short* gB1 = w1t + ((size_t)e * FFf + n0 + wv * 16 + rlo) * Dm + ch * 8;
  const unsigned short* gB3 = w3t + ((size_t)e * FFf + n0 + wv * 16 + rlo) * Dm + ch * 8;
  const int lwA0 = (wv * 16 + rlo) * 40 + ch * 8;
  const int lwA1 = (64 + wv * 16 + rlo) * 40 + ch * 8;
  const int lwB  = (wv * 16 + rlo) * 40 + ch * 8;
  int roA[4], roB[2];
  #pragma unroll
  for (int mf = 0; mf < 4; ++mf) roA[mf] = (wm * 64 + mf * 16 + (lane & 15)) * 40 + (lane >> 4) * 8;
  #pragma unroll
  for (int nf = 0; nf < 2; ++nf) roB[nf] = (wn * 32 + nf * 16 + (lane & 15)) * 40 + (lane >> 4) * 8;

  int4v ra0 = *(const int4v*)(gA[0]);
  int4v ra1 = *(const int4v*)(gA[1]);
  int4v rb1 = *(const int4v*)(gB1);
  int4v rb3 = *(const int4v*)(gB3);

  constexpr int NT = Dm / 32;
  for (int kt = 0; kt < NT; ++kt) {
    __syncthreads();
    *(int4v*)&As[lwA0] = ra0;
    *(int4v*)&As[lwA1] = ra1;
    *(int4v*)&B1s[lwB] = rb1;
    *(int4v*)&B3s[lwB] = rb3;
    __syncthreads();
    if (kt + 1 < NT) {
      int ko = (kt + 1) * 32;
      ra0 = *(const int4v*)(gA[0] + ko);
      ra1 = *(const int4v*)(gA[1] + ko);
      rb1 = *(const int4v*)(gB1 + ko);
      rb3 = *(const int4v*)(gB3 + ko);
    }
    short8 a[4], b1f[2], b3f[2];
    #pragma unroll
    for (int mf = 0; mf < 4; ++mf) a[mf] = *(const short8*)&As[roA[mf]];
    #pragma unroll
    for (int nf = 0; nf < 2; ++nf) {
      b1f[nf] = *(const short8*)&B1s[roB[nf]];
      b3f[nf] = *(const short8*)&B3s[roB[nf]];
    }
    #pragma unroll
    for (int mf = 0; mf < 4; ++mf)
      #pragma unroll
      for (int nf = 0; nf < 2; ++nf) {
        acc1[mf][nf] = __builtin_amdgcn_mfma_f32_16x16x32_bf16(a[mf], b1f[nf], acc1[mf][nf], 0, 0, 0);
        acc3[mf][nf] = __builtin_amdgcn_mfma_f32_16x16x32_bf16(a[mf], b3f[nf], acc3[mf][nf], 0, 0, 0);
      }
  }
  const int rbase = (lane >> 4) * 4, ccol = lane & 15;
  #pragma unroll
  for (int mf = 0; mf < 4; ++mf)
    #pragma unroll
    for (int rg = 0; rg < 4; ++rg) {
      int mrow = wm * 64 + mf * 16 + rbase + rg;
      if (m0 + mrow < cntE) {
        size_t arow = (size_t)(offsE + m0 + mrow) * FFf;
        #pragma unroll
        for (int nf = 0; nf < 2; ++nf) {
          float h1 = acc1[mf][nf][rg];
          float h3 = acc3[mf][nf][rg];
          float sv = h1 / (1.f + __expf(-h1)) * h3;
          act[arow + n0 + wn * 32 + nf * 16 + ccol] = f2bf(sv);
        }
      }
    }
}

// ---------------------------------------------------------------------------
// MoE stage 2
__global__ __launch_bounds__(256) void moe_stage2(const unsigned short* __restrict__ act,
                                                  const unsigned short* __restrict__ w2t,
                                                  const int* __restrict__ cnt,
                                                  const int* __restrict__ offs,
                                                  const int* __restrict__ ltok,
                                                  const float* __restrict__ lw,
                                                  float* __restrict__ hout) {
  const int e = blockIdx.z;
  const int cntE = cnt[e];
  const int m0 = blockIdx.y * 128;
  if (m0 >= cntE) return;
  const int n0 = blockIdx.x * 128;
  const int offsE = offs[e];
  const int tid = threadIdx.x;
  const int wv = tid >> 6, lane = tid & 63;
  const int wm = wv >> 1, wn = wv & 1;

  __shared__ unsigned short As[128 * 40];
  __shared__ unsigned short Bs[128 * 40];

  f32x4 acc[4][4];
  #pragma unroll
  for (int i = 0; i < 4; ++i)
    #pragma unroll
    for (int j = 0; j < 4; ++j) acc[i][j] = (f32x4){0.f, 0.f, 0.f, 0.f};
  const int rlo = lane >> 2, ch = lane & 3;
  const unsigned short* gA[2];
  const unsigned short* gB[2];
  int lwA[2], lwBo[2];
  #pragma unroll
  for (int p = 0; p < 2; ++p) {
    int row = p * 64 + wv * 16 + rlo;
    int ri = (m0 + row < cntE) ? (m0 + row) : 0;
    gA[p] = act + (size_t)(offsE + ri) * FFf + ch * 8;
    gB[p] = w2t + ((size_t)e * Dm + n0 + row) * FFf + ch * 8;
    lwA[p] = row * 40 + ch * 8;
    lwBo[p] = row * 40 + ch * 8;
  }
  int roA[4], roB[4];
  #pragma unroll
  for (int mf = 0; mf < 4; ++mf) roA[mf] = (wm * 64 + mf * 16 + (lane & 15)) * 40 + (lane >> 4) * 8;
  #pragma unroll
  for (int nf = 0; nf < 4; ++nf) roB[nf] = (wn * 64 + nf * 16 + (lane & 15)) * 40 + (lane >> 4) * 8;

  int4v ra0 = *(const int4v*)(gA[0]);
  int4v ra1 = *(const int4v*)(gA[1]);
  int4v rb0 = *(const int4v*)(gB[0]);
  int4v rb1 = *(const int4v*)(gB[1]);

  constexpr int NT = FFf / 32;
  for (int kt = 0; kt < NT; ++kt) {
    __syncthreads();
    *(int4v*)&As[lwA[0]] = ra0;
    *(int4v*)&As[lwA[1]] = ra1;
    *(int4v*)&Bs[lwBo[0]] = rb0;
    *(int4v*)&Bs[lwBo[1]] = rb1;
    __syncthreads();
    if (kt + 1 < NT) {
      int ko = (kt + 1) * 32;
      ra0 = *(const int4v*)(gA[0] + ko);
      ra1 = *(const int4v*)(gA[1] + ko);
      rb0 = *(const int4v*)(gB[0] + ko);
      rb1 = *(const int4v*)(gB[1] + ko);
    }
    short8 a[4], bfr[4];
    #pragma unroll
    for (int mf = 0; mf < 4; ++mf) a[mf] = *(const short8*)&As[roA[mf]];
    #pragma unroll
    for (int nf = 0; nf < 4; ++nf) bfr[nf] = *(const short8*)&Bs[roB[nf]];
    #pragma unroll
    for (int mf = 0; mf < 4; ++mf)
      #pragma unroll
      for (int nf = 0; nf < 4; ++nf)
        acc[mf][nf] = __builtin_amdgcn_mfma_f32_16x16x32_bf16(a[mf], bfr[nf], acc[mf][nf], 0, 0, 0);
  }
  const int rbase = (lane >> 4) * 4, ccol = lane & 15;
  #pragma unroll
  for (int mf = 0; mf < 4; ++mf)
    #pragma unroll
    for (int rg = 0; rg < 4; ++rg) {
      int prow = m0 + wm * 64 + mf * 16 + rbase + rg;
      if (prow < cntE) {
        int tok = ltok[e * Tn + prow];
        float w = lw[e * Tn + prow];
        #pragma unroll
        for (int nf = 0; nf < 4; ++nf)
          atomicAdd(&hout[(size_t)tok * Dm + n0 + wn * 64 + nf * 16 + ccol],
                    w * acc[mf][nf][rg]);
      }
    }
}

// ---------------------------------------------------------------------------
extern "C" void kernel_launch(void* const* d_in, const int* in_sizes, int n_in,
                              void* d_out, int out_size, void* d_ws, size_t ws_size,
                              hipStream_t stream) {
  const float* hidden = (const float*)d_in[0];
  const float* prev  = (const float*)d_in[2];
  const float* wq    = (const float*)d_in[3];
  const float* wk    = (const float*)d_in[4];
  const float* wv    = (const float*)d_in[5];
  const float* wo    = (const float*)d_in[6];
  const float* mixw  = (const float*)d_in[7];
  const float* mixb  = (const float*)d_in[8];
  const float* gatew = (const float*)d_in[9];
  const float* w1    = (const float*)d_in[10];
  const float* w2    = (const float*)d_in[11];
  const float* w3    = (const float*)d_in[12];
  const float* ln1   = (const float*)d_in[13];
  const float* ln2   = (const float*)d_in[14];
  const float* compw = (const float*)d_in[15];
  const float* compb = (const float*)d_in[16];

  float* out_h    = (float*)d_out;
  float* out_mix  = out_h + 4194304;
  float* out_comp = out_h + 8388608;

  // ---- workspace layout (bytes) ----
  constexpr size_t SZ_WT = (size_t)Ee * FFf * Dm * 2;        // 46,137,344
  constexpr size_t O_W1T = 0;                                 // w2t aliases this after stage1
  constexpr size_t O_W3T = SZ_WT;
  constexpr size_t O_SW  = 2 * SZ_WT;                         // 92,274,688
  constexpr size_t O_WQH = O_SW + 0,         O_WQL = O_SW + 2097152;
  constexpr size_t O_WKH = O_SW + 4194304,   O_WKL = O_SW + 4718592;
  constexpr size_t O_WVH = O_SW + 5242880,   O_WVL = O_SW + 5767168;
  constexpr size_t O_WOH = O_SW + 6291456,   O_WOL = O_SW + 8388608;
  constexpr size_t O_MXH = O_SW + 10485760,  O_MXL = O_SW + 14680064;
  constexpr size_t O_CPH = O_SW + 18874368,  O_CPL = O_SW + 19398656;
  constexpr size_t O_META = O_SW + 19922944;                  // 112,197,632
  constexpr size_t O_CNT  = O_META, O_OFF = O_META + 128;
  constexpr size_t O_LTOK = O_META + 256, O_LW = O_META + 131328;
  constexpr size_t O_BUF  = 112460288;
  constexpr size_t O_XF   = O_BUF;                 // 16 MB (attnf alias; act overlap)
  constexpr size_t O_QF   = O_BUF + 16777216;      // 16 MB (curf alias; act overlap)
  constexpr size_t O_KF   = O_BUF + 33554432;      //  4 MB (act overlap)
  constexpr size_t O_VF   = O_BUF + 37748736;      //  4 MB (act overlap)
  constexpr size_t O_ACT  = O_BUF;                 // 46,137,344 (bf16 act)
  constexpr size_t O_H2B  = O_BUF + 46137344;      //  8 MB
  constexpr size_t WS_NEED = O_H2B + 8388608;      // 166,986,240

  if (ws_size < WS_NEED || out_size < 9437184 || n_in < 17 ||
      in_sizes[0] != 4194304 || in_sizes[10] != 23068672 || in_sizes[7] != 2097152) {
    fprintf(stderr, "kernel_launch: precondition failed ws=%zu need=%zu out=%d n_in=%d\n",
            ws_size, WS_NEED, out_size, n_in);
    return;
  }

  char* ws = (char*)d_ws;
  unsigned short* w1t = (unsigned short*)(ws + O_W1T);
  unsigned short* w3t = (unsigned short*)(ws + O_W3T);
  unsigned short* w2t = (unsigned short*)(ws + O_W1T);   // alias (after stage1)
  unsigned short* wqh = (unsigned short*)(ws + O_WQH), *wql = (unsigned short*)(ws + O_WQL);
  unsigned short* wkh = (unsigned short*)(ws + O_WKH), *wkl = (unsigned short*)(ws + O_WKL);
  unsigned short* wvh = (unsigned short*)(ws + O_WVH), *wvl = (unsigned short*)(ws + O_WVL);
  unsigned short* woh = (unsigned short*)(ws + O_WOH), *wol = (unsigned short*)(ws + O_WOL);
  unsigned short* mxh = (unsigned short*)(ws + O_MXH), *mxl = (unsigned short*)(ws + O_MXL);
  unsigned short* cph = (unsigned short*)(ws + O_CPH), *cpl = (unsigned short*)(ws + O_CPL);
  int*   cnt  = (int*)(ws + O_CNT);
  int*   offs = (int*)(ws + O_OFF);
  int*   ltok = (int*)(ws + O_LTOK);
  float* lwgt = (float*)(ws + O_LW);
  float* xf    = (float*)(ws + O_XF);
  float* attnf = (float*)(ws + O_XF);    // alias: xf dead after QKV GEMMs
  float* qf    = (float*)(ws + O_QF);
  float* curf  = (float*)(ws + O_QF);    // alias: qf dead after attention
  float* kfb   = (float*)(ws + O_KF);
  float* vfb   = (float*)(ws + O_VF);
  unsigned short* act = (unsigned short*)(ws + O_ACT);  // over xf/qf/kf/vf (all dead)
  unsigned short* h2b = (unsigned short*)(ws + O_H2B);

  hipMemsetAsync(cnt, 0, 8 * sizeof(int), stream);

  // MoE weight transposes (w2 deferred until after stage1 — aliases w1t)
  conv_transpose_bf16<<<dim3(88, 32, 8), 256, 0, stream>>>(w1, w1t, 1024, 2816);
  conv_transpose_bf16<<<dim3(88, 32, 8), 256, 0, stream>>>(w3, w3t, 1024, 2816);
  // pre-gate weight split+transpose ([K][N] fp32 -> [N][K] bf16 hi/lo)
  split_transpose<<<dim3(32, 32), 256, 0, stream>>>(wq, wqh, wql, 1024, 1024);
  split_transpose<<<dim3(8, 32), 256, 0, stream>>>(wk, wkh, wkl, 1024, 256);
  split_transpose<<<dim3(8, 32), 256, 0, stream>>>(wv, wvh, wvl, 1024, 256);
  split_transpose<<<dim3(32, 32), 256, 0, stream>>>(wo, woh, wol, 1024, 1024);
  split_transpose<<<dim3(32, 64), 256, 0, stream>>>(mixw, mxh, mxl, 2048, 1024);
  split_transpose<<<dim3(8, 32), 256, 0, stream>>>(compw, cph, cpl, 1024, 256);

  // pre-gate path (split-bf16 3-term, fp32-class accuracy)
  rms1_kernel<<<Tn, 256, 0, stream>>>(hidden, ln1, xf);
  gemm_split3<0, 0><<<dim3(8, 32), 256, 0, stream>>>(xf, nullptr, wqh, wql, qf,
                                                     Tn, 1024, 1024, 1024, nullptr, nullptr, nullptr);
  gemm_split3<0, 0><<<dim3(2, 32), 256, 0, stream>>>(xf, nullptr, wkh, wkl, kfb,
                                                     Tn, 256, 1024, 1024, nullptr, nullptr, nullptr);
  gemm_split3<0, 0><<<dim3(2, 32), 256, 0, stream>>>(xf, nullptr, wvh, wvl, vfb,
                                                     Tn, 256, 1024, 1024, nullptr, nullptr, nullptr);
  attn_split<<<dim3(16, 64), 256, 0, stream>>>(qf, kfb, vfb, attnf);
  gemm_split3<0, 0><<<dim3(8, 32), 256, 0, stream>>>(attnf, nullptr, woh, wol, curf,
                                                     Tn, 1024, 1024, 1024, nullptr, nullptr, nullptr);
  // mixed = [cur, prev] @ mix_w + b ; h = hidden + mixed
  gemm_split3<1, 2><<<dim3(8, 32), 256, 0, stream>>>(curf, prev, mxh, mxl, out_mix,
                                                     Tn, 1024, 2048, 1024, mixb, hidden, out_h);
  // exact fp32 gate + top-2 (numerics identical to R1)
  rms2_gate<<<Tn, 256, 0, stream>>>(out_h, ln2, gatew, h2b, cnt, ltok, lwgt);
  excl_scan<<<1, 64, 0, stream>>>(cnt, offs);

  // MoE (bf16 MFMA, grouped by expert)
  moe_stage1<<<dim3(44, 32, 8), 256, 0, stream>>>(h2b, w1t, w3t, cnt, offs, ltok, act);
  conv_transpose_bf16<<<dim3(32, 88, 8), 256, 0, stream>>>(w2, w2t, 2816, 1024);
  moe_stage2<<<dim3(8, 32, 8), 256, 0, stream>>>(act, w2t, cnt, offs, ltok, lwgt, out_h);

  // compression head
  gemm_split3<0, 1><<<dim3(2, 32), 256, 0, stream>>>(out_h, nullptr, cph, cpl, out_comp,
                                                     Tn, 256, 1024, 1024, compb, nullptr, nullptr);
}